// Round 6
// baseline (264.901 us; speedup 1.0000x reference)
//
#include <hip/hip_runtime.h>

// B=2, S=4096, C=2048, HD=128, H=16
// GEMM: M=8192 (B*S), N=6144 (3*C), K=2048; out = concat(q,k,v) f32 [8192,2048] each.

#define M_DIM 8192
#define N_DIM 6144
#define K_DIM 2048
#define NKT 32            // K tiles of 64
#define EPS_RMS 1.1920929e-07f

typedef __bf16 bf16x8 __attribute__((ext_vector_type(8)));
typedef float f32x4 __attribute__((ext_vector_type(4)));

__device__ __forceinline__ void gload16(const void* g, void* l) {
  __builtin_amdgcn_global_load_lds(
      (const __attribute__((address_space(1))) unsigned int*)g,
      (__attribute__((address_space(3))) unsigned int*)l, 16, 0, 0);
}

__device__ __forceinline__ unsigned short f2bf(float f) {
  union { float f; unsigned u; } x; x.f = f;
  unsigned r = x.u + 0x7FFFu + ((x.u >> 16) & 1u);   // RNE
  return (unsigned short)(r >> 16);
}

__global__ void __launch_bounds__(256) cvt_kernel(const float* __restrict__ s,
                                                  unsigned short* __restrict__ d, int n4) {
  int i = blockIdx.x * blockDim.x + threadIdx.x;
  const int stride = gridDim.x * blockDim.x;
  for (; i < n4; i += stride) {
    const float4 v = reinterpret_cast<const float4*>(s)[i];
    ushort4 o;
    o.x = f2bf(v.x); o.y = f2bf(v.y); o.z = f2bf(v.z); o.w = f2bf(v.w);
    reinterpret_cast<ushort4*>(d)[i] = o;
  }
}

#define LDS4(ARR, OFF) (*(const f32x4*)((const char*)(ARR) + (OFF)))

#define MFMA16(MH)                                                                   \
  {                                                                                  \
    _Pragma("unroll")                                                                \
    for (int mf4 = 0; mf4 < 4; ++mf4) {                                              \
      _Pragma("unroll")                                                              \
      for (int nf4 = 0; nf4 < 4; ++nf4) {                                            \
        acc[(MH) * 4 + mf4][nf4] = __builtin_amdgcn_mfma_f32_16x16x32_bf16(          \
            __builtin_bit_cast(bf16x8, Af[mf4]),                                     \
            __builtin_bit_cast(bf16x8, Bf[nf4]), acc[(MH) * 4 + mf4][nf4], 0, 0, 0); \
      }                                                                              \
    }                                                                                \
  }

#define FENCE asm volatile("" ::: "memory")

// 256x256 tile, BK=64, 8 waves (2M x 4N), per-wave 128x64, 16x16x32 MFMA.
// 4 phases/K-tile by (m-half, k-slice): reads 8/4/8/4 (24 total, minimal),
// MFMA 16/phase, 2 barriers/phase (template), one 2-load stage set per phase:
//   ph0(mh0,ks0): stage B(k0)'   ph1(mh1,ks0): stage A(q0,q2)'
//   ph2(mh1,ks1): stage A(q1,q3)'  ph3(mh0,ks1): stage B(k1)'
// Waits: vmcnt(4) before B2 of ph0/ph1/ph3 (tail: 2/0/-), max 8 outstanding,
// every staged set has >=3 phases of landing slack. Never vmcnt(0) mid-loop.
// LDS: A = 2buf x 4 quarters(64r x 64k) = 64 KB (chunk^=row&7 swizzle);
//      B = 2buf x 2 k-halves(256r x 32k) = 64 KB (slot^= (row>>1)&3 swizzle).
__global__ void __launch_bounds__(512, 2) gemm_fused(
    const unsigned short* __restrict__ xbf, const unsigned short* __restrict__ wbf,
    const float* __restrict__ rope,
    const float* __restrict__ bq, const float* __restrict__ bk, const float* __restrict__ bv,
    const float* __restrict__ qnw, const float* __restrict__ knw,
    float* __restrict__ dout) {
  const int id = blockIdx.x;
  // XCD-aware, bm-inner: XCD x owns bm in [4x,4x+4), bm fastest -> small L2 set.
  const int xcd = id & 7;
  const int jb = id >> 3;                // 0..95
  const int bm = (xcd << 2) | (jb & 3);  // 0..31
  const int bn = jb >> 2;                // 0..23
  const int m0 = bm << 8, n0 = bn << 8;
  const int tid = threadIdx.x;
  const int w = tid >> 6, l = tid & 63;
  const int l15 = l & 15, lhi = l >> 4;
  const int wr = w >> 2, wc = w & 3;

  __shared__ __align__(16) unsigned short As[32768];   // 64 KB
  __shared__ __align__(16) unsigned short Bs[32768];   // 64 KB

  // ---- A staging: quarter q = 64 rows x 64 k = 8 KB = 1 gload/thread ----
  const int cA = (tid & 7) ^ ((tid >> 3) & 7);
  const unsigned short* aSrc = xbf + ((size_t)(m0 + (tid >> 3)) << 11) + (cA << 3);
  char* aDst = (char*)As + (w << 10);
#define STA(KT, Q) gload16(aSrc + ((size_t)(Q) << 17) + ((KT) << 6), aDst + ((((KT) & 1) << 15) + ((Q) << 13)))

  // ---- B staging: k-half unit = 256 rows x 32 k = 16 KB = 2 gloads/thread ----
  const int cB = (tid & 3) ^ ((tid >> 3) & 3);
  const unsigned short* bSrc = wbf + ((size_t)(n0 + (tid >> 2)) << 11) + (cB << 3);
  char* bDst = (char*)Bs + (w << 10);
#define STB(KT, KH)                                                                        \
  do {                                                                                     \
    gload16(bSrc + ((KT) << 6) + ((KH) << 5), bDst + ((((KT) & 1) << 15) + ((KH) << 14))); \
    gload16(bSrc + ((size_t)128 << 11) + ((KT) << 6) + ((KH) << 5),                        \
            bDst + ((((KT) & 1) << 15) + ((KH) << 14)) + 8192);                            \
  } while (0)

  // ---- read-side swizzled byte offsets ----
  const int sl0 = ((lhi ^ (l15 & 7)) << 4);        // A k-slots 0..3 (k 0..31)
  const int sl1 = (((lhi + 4) ^ (l15 & 7)) << 4);  // A k-slots 4..7 (k 32..63)
  const unsigned aB0 = (unsigned)((wr << 14) + (l15 << 7) + sl0);
  const unsigned aB1 = (unsigned)((wr << 14) + (l15 << 7) + sl1);
  const unsigned bB = (unsigned)((wc << 12) + (l15 << 6) + ((lhi ^ ((l15 >> 1) & 3)) << 4));

  f32x4 acc[8][4];
#pragma unroll
  for (int i = 0; i < 8; ++i)
#pragma unroll
    for (int jj = 0; jj < 4; ++jj) acc[i][jj] = (f32x4){0.f, 0.f, 0.f, 0.f};

  f32x4 Af[4];   // current (mh, ks) A fragments
  f32x4 Bf[4];   // current ks B fragments (reused across both mh phases)

  // ---- prologue: issue kt0 sets in deadline order; drain first two ----
  STB(0, 0);
  STA(0, 0); STA(0, 2);
  STA(0, 1); STA(0, 3);
  STB(0, 1);
  asm volatile("s_waitcnt vmcnt(4)" ::: "memory");   // B(k0), A(q0,q2) landed
  __builtin_amdgcn_s_barrier();
  FENCE;

  unsigned abuf = 0, bbuf = 0;
  for (int kt = 0; kt < NKT; ++kt) {
    const bool nl = (kt < NKT - 1);
    // ---- ph0 (mh0, ks0): 4 A + 4 B reads; stage B(k0)(kt+1) ----
    Af[0] = LDS4(As, abuf + aB0);        Af[1] = LDS4(As, abuf + aB0 + 2048);
    Af[2] = LDS4(As, abuf + aB0 + 4096); Af[3] = LDS4(As, abuf + aB0 + 6144);
    Bf[0] = LDS4(Bs, bbuf + bB);         Bf[1] = LDS4(Bs, bbuf + bB + 1024);
    Bf[2] = LDS4(Bs, bbuf + bB + 2048);  Bf[3] = LDS4(Bs, bbuf + bB + 3072);
    if (nl) STB(kt + 1, 0);
    __builtin_amdgcn_s_barrier();
    FENCE;
    __builtin_amdgcn_s_setprio(1);
    MFMA16(0);
    __builtin_amdgcn_s_setprio(0);
    if (nl) { asm volatile("s_waitcnt vmcnt(4)" ::: "memory"); }   // A(q1,q3) this kt
    else    { asm volatile("s_waitcnt vmcnt(2)" ::: "memory"); }
    __builtin_amdgcn_s_barrier();
    FENCE;
    // ---- ph1 (mh1, ks0): 4 A reads (B regs reused); stage A(q0,q2)(kt+1) ----
    Af[0] = LDS4(As, abuf + aB0 + 8192);  Af[1] = LDS4(As, abuf + aB0 + 10240);
    Af[2] = LDS4(As, abuf + aB0 + 12288); Af[3] = LDS4(As, abuf + aB0 + 14336);
    if (nl) { STA(kt + 1, 0); STA(kt + 1, 2); }
    __builtin_amdgcn_s_barrier();
    FENCE;
    __builtin_amdgcn_s_setprio(1);
    MFMA16(1);
    __builtin_amdgcn_s_setprio(0);
    if (nl) { asm volatile("s_waitcnt vmcnt(4)" ::: "memory"); }   // B(k1) this kt
    else    { asm volatile("s_waitcnt vmcnt(0)" ::: "memory"); }
    __builtin_amdgcn_s_barrier();
    FENCE;
    // ---- ph2 (mh1, ks1): 4 A + 4 B reads; stage A(q1,q3)(kt+1) ----
    Af[0] = LDS4(As, abuf + aB1 + 8192);  Af[1] = LDS4(As, abuf + aB1 + 10240);
    Af[2] = LDS4(As, abuf + aB1 + 12288); Af[3] = LDS4(As, abuf + aB1 + 14336);
    Bf[0] = LDS4(Bs, bbuf + bB + 16384);  Bf[1] = LDS4(Bs, bbuf + bB + 17408);
    Bf[2] = LDS4(Bs, bbuf + bB + 18432);  Bf[3] = LDS4(Bs, bbuf + bB + 19456);
    if (nl) { STA(kt + 1, 1); STA(kt + 1, 3); }
    __builtin_amdgcn_s_barrier();
    FENCE;
    __builtin_amdgcn_s_setprio(1);
    MFMA16(1);
    __builtin_amdgcn_s_setprio(0);
    __builtin_amdgcn_s_barrier();
    FENCE;
    // ---- ph3 (mh0, ks1): 4 A reads (B regs reused); stage B(k1)(kt+1) ----
    Af[0] = LDS4(As, abuf + aB1);        Af[1] = LDS4(As, abuf + aB1 + 2048);
    Af[2] = LDS4(As, abuf + aB1 + 4096); Af[3] = LDS4(As, abuf + aB1 + 6144);
    if (nl) STB(kt + 1, 1);
    __builtin_amdgcn_s_barrier();
    FENCE;
    __builtin_amdgcn_s_setprio(1);
    MFMA16(0);
    __builtin_amdgcn_s_setprio(0);
    if (nl) { asm volatile("s_waitcnt vmcnt(4)" ::: "memory"); }   // B(k0)',A(q0,q2)' kt+1
    __builtin_amdgcn_s_barrier();
    FENCE;
    abuf ^= 32768u; bbuf ^= 32768u;
  }

  // ---- fused epilogue: bias (+ per-head RMSNorm + RoPE for q,k) ----
  float* scr = (float*)As;                       // [8 waves][128 rows] partials
  const int sec = bn >> 3;                       // 0=q 1=k 2=v
  const int nsec = (n0 & 2047) + (wc << 6);      // col-in-section base (+nf*16+l15)
  const float* bias = sec == 0 ? bq : (sec == 1 ? bk : bv);
  float biasv[4];
#pragma unroll
  for (int nf = 0; nf < 4; ++nf) biasv[nf] = bias[nsec + nf * 16 + l15];
  const size_t outBase = ((size_t)sec << 24);

  if (sec < 2) {
    const float* nwp = sec ? knw : qnw;
    const int colh = (wc & 1) << 6;              // col-in-head base for this wave
    float nwv[4];
#pragma unroll
    for (int nf = 0; nf < 4; ++nf) nwv[nf] = nwp[colh + nf * 16 + l15];
    float ssv[8][4];
#pragma unroll
    for (int mf = 0; mf < 8; ++mf) {
#pragma unroll
      for (int jj = 0; jj < 4; ++jj) {
        float ss = 0.f;
#pragma unroll
        for (int nf = 0; nf < 4; ++nf) {
          const float t = acc[mf][nf][jj] + biasv[nf];
          ss += t * t;
        }
        ss += __shfl_xor(ss, 1);
        ss += __shfl_xor(ss, 2);
        ss += __shfl_xor(ss, 4);
        ss += __shfl_xor(ss, 8);
        ssv[mf][jj] = ss;                        // sum over this wave's 64 cols
      }
    }
    if (l15 == 0) {
#pragma unroll
      for (int mf = 0; mf < 8; ++mf)
#pragma unroll
        for (int jj = 0; jj < 4; ++jj)
          scr[(w << 7) + mf * 16 + (lhi << 2) + jj] = ssv[mf][jj];
    }
    __syncthreads();
#pragma unroll
    for (int mf = 0; mf < 8; ++mf) {
#pragma unroll
      for (int jj = 0; jj < 4; ++jj) {
        const float tot = ssv[mf][jj] + scr[((w ^ 1) << 7) + mf * 16 + (lhi << 2) + jj];
        const float inv = rsqrtf(tot * (1.0f / 128.0f) + EPS_RMS);
        const int m = m0 + (wr << 7) + mf * 16 + (lhi << 2) + jj;
        const float* rp = rope + ((size_t)(m & 4095) << 8);
        float* orow = dout + outBase + ((size_t)m << 11) + nsec + l15;
#pragma unroll
        for (int nf = 0; nf < 4; ++nf) {
          const float tn = (acc[mf][nf][jj] + biasv[nf]) * inv * nwv[nf];
          const float pn = __shfl_xor(tn, 1);     // partner col^1
          const int ch = colh + nf * 16 + l15;    // col in head
          const int jr = ch >> 1;
          const float o = fmaf(rp[jr << 2], tn, rp[(jr << 2) + 1 + (ch & 1)] * pn);
          orow[nf << 4] = o;
        }
      }
    }
  } else {
#pragma unroll
    for (int mf = 0; mf < 8; ++mf)
#pragma unroll
      for (int jj = 0; jj < 4; ++jj) {
        const int m = m0 + (wr << 7) + mf * 16 + (lhi << 2) + jj;
        float* orow = dout + outBase + ((size_t)m << 11) + nsec + l15;
#pragma unroll
        for (int nf = 0; nf < 4; ++nf) orow[nf << 4] = acc[mf][nf][jj] + biasv[nf];
      }
  }
}

extern "C" void kernel_launch(void* const* d_in, const int* in_sizes, int n_in,
                              void* d_out, int out_size, void* d_ws, size_t ws_size,
                              hipStream_t stream) {
  const float* x = (const float*)d_in[0];
  const float* rope = (const float*)d_in[1];
  const float* wq = (const float*)d_in[2];
  const float* bq = (const float*)d_in[3];
  const float* wk = (const float*)d_in[4];
  const float* bk = (const float*)d_in[5];
  const float* wv = (const float*)d_in[6];
  const float* bv = (const float*)d_in[7];
  const float* qnw = (const float*)d_in[8];
  const float* knw = (const float*)d_in[9];

  unsigned short* xbf = (unsigned short*)d_ws;                 // 32 MB
  unsigned short* wbf = xbf + (size_t)M_DIM * K_DIM;           // 24 MB

  cvt_kernel<<<2048, 256, 0, stream>>>(x, xbf, M_DIM * K_DIM / 4);
  cvt_kernel<<<1024, 256, 0, stream>>>(wq, wbf, K_DIM * K_DIM / 4);
  cvt_kernel<<<1024, 256, 0, stream>>>(wk, wbf + (size_t)K_DIM * K_DIM, K_DIM * K_DIM / 4);
  cvt_kernel<<<1024, 256, 0, stream>>>(wv, wbf + (size_t)2 * K_DIM * K_DIM, K_DIM * K_DIM / 4);

  gemm_fused<<<(M_DIM / 256) * (N_DIM / 256), 512, 0, stream>>>(
      xbf, wbf, rope, bq, bk, bv, qnw, knw, (float*)d_out);
}